// Round 2
// baseline (1787.053 us; speedup 1.0000x reference)
//
#include <hip/hip_runtime.h>
#include <hip/hip_bf16.h>

#define N_NODES 100000
#define N_EDGES 600000
#define HID 128
#define D_BOND 16
#define D_IN   (HID + D_BOND)   // 144
#define NB_CHUNKS 98            // ceil(100000/1024)

__device__ __forceinline__ float bf2f(unsigned int u) {
    return __uint_as_float((u & 0xffffu) << 16);
}
__device__ __forceinline__ unsigned short f2bf(float f) {
    unsigned int x = __float_as_uint(f);
    x += 0x7fffu + ((x >> 16) & 1u);          // round-to-nearest-even
    return (unsigned short)(x >> 16);
}

// ---------------------------------------------------------------- CSR build
__global__ __launch_bounds__(256) void k_hist(const int* __restrict__ dst,
                                              int* __restrict__ cnt) {
    int e = blockIdx.x * 256 + threadIdx.x;
    if (e < N_EDGES) atomicAdd(&cnt[dst[e]], 1);
}

__global__ __launch_bounds__(256) void k_blocksum(const int* __restrict__ cnt,
                                                  int* __restrict__ bsum) {
    __shared__ int red[256];
    const int b = blockIdx.x, t = threadIdx.x;
    const int base = b * 1024 + t * 4;
    int s = 0;
#pragma unroll
    for (int i = 0; i < 4; ++i) { int n = base + i; if (n < N_NODES) s += cnt[n]; }
    red[t] = s; __syncthreads();
    for (int o = 128; o > 0; o >>= 1) { if (t < o) red[t] += red[t + o]; __syncthreads(); }
    if (t == 0) bsum[b] = red[0];
}

__global__ __launch_bounds__(128) void k_scan_bsum(const int* __restrict__ bsum,
                                                   int* __restrict__ boff,
                                                   int* __restrict__ rowptr) {
    __shared__ int s[128];
    const int t = threadIdx.x;
    const int v = (t < NB_CHUNKS) ? bsum[t] : 0;
    s[t] = v; __syncthreads();
    for (int o = 1; o < 128; o <<= 1) {
        int add = 0; if (t >= o) add = s[t - o];
        __syncthreads();
        s[t] += add; __syncthreads();
    }
    if (t < NB_CHUNKS) boff[t] = s[t] - v;   // exclusive block offset
    if (t == 0) rowptr[N_NODES] = N_EDGES;
}

__global__ __launch_bounds__(256) void k_scan_chunk(const int* __restrict__ cnt,
                                                    const int* __restrict__ boff,
                                                    int* __restrict__ rowptr,
                                                    int* __restrict__ wpos) {
    __shared__ int s[256];
    const int b = blockIdx.x, t = threadIdx.x;
    const int base = b * 1024 + t * 4;
    int v[4]; int ts = 0;
#pragma unroll
    for (int i = 0; i < 4; ++i) { int n = base + i; v[i] = (n < N_NODES) ? cnt[n] : 0; ts += v[i]; }
    s[t] = ts; __syncthreads();
    for (int o = 1; o < 256; o <<= 1) {
        int add = 0; if (t >= o) add = s[t - o];
        __syncthreads();
        s[t] += add; __syncthreads();
    }
    int run = s[t] - ts + boff[b];           // thread-exclusive prefix
#pragma unroll
    for (int i = 0; i < 4; ++i) {
        int n = base + i;
        if (n < N_NODES) { rowptr[n] = run; wpos[n] = run; }
        run += v[i];
    }
}

__global__ __launch_bounds__(256) void k_fill(const int* __restrict__ dst,
                                              int* __restrict__ wpos,
                                              int* __restrict__ eidx) {
    int e = blockIdx.x * 256 + threadIdx.x;
    if (e < N_EDGES) { int p = atomicAdd(&wpos[dst[e]], 1); eidx[p] = e; }
}

// ------------------------------------------------------------ H = relu([x[src];ea] @ Wi + bi)
__global__ __launch_bounds__(256) void k_h0(const float* __restrict__ x,
                                            const float* __restrict__ ea,
                                            const float* __restrict__ Wi,
                                            const float* __restrict__ bi,
                                            const int* __restrict__ src,
                                            unsigned short* __restrict__ H) {
    __shared__ float A[32][D_IN + 1];       // 18.6 KB
    __shared__ int s_src[32];
    const int e0 = blockIdx.x * 32;
    const int t = threadIdx.x;
    if (t < 32) s_src[t] = src[e0 + t];
    __syncthreads();
    for (int f = t; f < 1024; f += 256) {
        const int e = f >> 5, k4 = (f & 31) << 2;
        const float4 v = *reinterpret_cast<const float4*>(&x[(size_t)s_src[e] * HID + k4]);
        float* a = &A[e][k4];
        a[0] = v.x; a[1] = v.y; a[2] = v.z; a[3] = v.w;
    }
    if (t < 128) {
        const int e = t >> 2, k4 = (t & 3) << 2;
        const float4 v = *reinterpret_cast<const float4*>(&ea[(size_t)(e0 + e) * D_BOND + k4]);
        float* a = &A[e][HID + k4];
        a[0] = v.x; a[1] = v.y; a[2] = v.z; a[3] = v.w;
    }
    __syncthreads();
    const int eg = t >> 5, cg = t & 31;
    float acc[4][4] = {};
#pragma unroll 4
    for (int k = 0; k < D_IN; ++k) {
        const float4 w = *reinterpret_cast<const float4*>(&Wi[k * HID + (cg << 2)]);
        const float a0 = A[eg * 4 + 0][k], a1 = A[eg * 4 + 1][k];
        const float a2 = A[eg * 4 + 2][k], a3 = A[eg * 4 + 3][k];
        acc[0][0] = fmaf(a0, w.x, acc[0][0]); acc[0][1] = fmaf(a0, w.y, acc[0][1]);
        acc[0][2] = fmaf(a0, w.z, acc[0][2]); acc[0][3] = fmaf(a0, w.w, acc[0][3]);
        acc[1][0] = fmaf(a1, w.x, acc[1][0]); acc[1][1] = fmaf(a1, w.y, acc[1][1]);
        acc[1][2] = fmaf(a1, w.z, acc[1][2]); acc[1][3] = fmaf(a1, w.w, acc[1][3]);
        acc[2][0] = fmaf(a2, w.x, acc[2][0]); acc[2][1] = fmaf(a2, w.y, acc[2][1]);
        acc[2][2] = fmaf(a2, w.z, acc[2][2]); acc[2][3] = fmaf(a2, w.w, acc[2][3]);
        acc[3][0] = fmaf(a3, w.x, acc[3][0]); acc[3][1] = fmaf(a3, w.y, acc[3][1]);
        acc[3][2] = fmaf(a3, w.z, acc[3][2]); acc[3][3] = fmaf(a3, w.w, acc[3][3]);
    }
    const float4 bv = *reinterpret_cast<const float4*>(&bi[cg << 2]);
#pragma unroll
    for (int i = 0; i < 4; ++i) {
        const int e = e0 + eg * 4 + i;
        ushort4 o;
        o.x = f2bf(fmaxf(acc[i][0] + bv.x, 0.f));
        o.y = f2bf(fmaxf(acc[i][1] + bv.y, 0.f));
        o.z = f2bf(fmaxf(acc[i][2] + bv.z, 0.f));
        o.w = f2bf(fmaxf(acc[i][3] + bv.w, 0.f));
        *reinterpret_cast<ushort4*>(&H[(size_t)e * HID + (cg << 2)]) = o;
    }
}

// ------------------------------------------------------------ agg[n] = sum_{e:dst=n} H[e]
__global__ __launch_bounds__(256) void k_agg(const unsigned short* __restrict__ H,
                                             const int* __restrict__ rowptr,
                                             const int* __restrict__ eidx,
                                             float* __restrict__ agg) {
    const int wid = (blockIdx.x * 256 + threadIdx.x) >> 6;  // one wave per node
    const int lane = threadIdx.x & 63;
    if (wid >= N_NODES) return;
    const int beg = rowptr[wid], end = rowptr[wid + 1];
    float a0 = 0.f, a1 = 0.f;
    for (int j = beg; j < end; ++j) {
        const int e = eidx[j];
        const unsigned int p = *reinterpret_cast<const unsigned int*>(&H[(size_t)e * HID + lane * 2]);
        a0 += bf2f(p);
        a1 += bf2f(p >> 16);
    }
    float2 o; o.x = a0; o.y = a1;
    *reinterpret_cast<float2*>(&agg[(size_t)wid * HID + lane * 2]) = o;
}

// ------------- H = relu(H0 + (agg[src]-H[rev]) @ Wh + bh), in place.
// rev(e) = e^1 is always inside the 32-aligned tile, so all H reads are
// tile-local and complete before the in-place writes.
// RECOMP=0: H currently holds H0 (first iteration) — read H0 from H itself.
// RECOMP=1: recompute H0 = relu([x[src];ea]@Wi+bi) in a first GEMM pass.
template<int RECOMP>
__global__ __launch_bounds__(256) void k_msg(const float* __restrict__ x,
                                             const float* __restrict__ ea,
                                             const float* __restrict__ agg,
                                             const float* __restrict__ Wi,
                                             const float* __restrict__ bi,
                                             const float* __restrict__ Wh,
                                             const float* __restrict__ bh,
                                             const int* __restrict__ src,
                                             const int* __restrict__ rev,
                                             unsigned short* H) {
    __shared__ float A[32][D_IN + 1];       // 18.6 KB; reused for X|ea then M
    __shared__ int s_src[32], s_rev[32];
    const int e0 = blockIdx.x * 32;
    const int t = threadIdx.x;
    if (t < 32) { s_src[t] = src[e0 + t]; s_rev[t] = rev[e0 + t]; }
    __syncthreads();
    const int eg = t >> 5, cg = t & 31;
    float h0r[4][4];

    if (RECOMP) {
        for (int f = t; f < 1024; f += 256) {
            const int e = f >> 5, k4 = (f & 31) << 2;
            const float4 v = *reinterpret_cast<const float4*>(&x[(size_t)s_src[e] * HID + k4]);
            float* a = &A[e][k4];
            a[0] = v.x; a[1] = v.y; a[2] = v.z; a[3] = v.w;
        }
        if (t < 128) {
            const int e = t >> 2, k4 = (t & 3) << 2;
            const float4 v = *reinterpret_cast<const float4*>(&ea[(size_t)(e0 + e) * D_BOND + k4]);
            float* a = &A[e][HID + k4];
            a[0] = v.x; a[1] = v.y; a[2] = v.z; a[3] = v.w;
        }
        __syncthreads();
        float acc[4][4] = {};
#pragma unroll 4
        for (int k = 0; k < D_IN; ++k) {
            const float4 w = *reinterpret_cast<const float4*>(&Wi[k * HID + (cg << 2)]);
            const float a0 = A[eg * 4 + 0][k], a1 = A[eg * 4 + 1][k];
            const float a2 = A[eg * 4 + 2][k], a3 = A[eg * 4 + 3][k];
            acc[0][0] = fmaf(a0, w.x, acc[0][0]); acc[0][1] = fmaf(a0, w.y, acc[0][1]);
            acc[0][2] = fmaf(a0, w.z, acc[0][2]); acc[0][3] = fmaf(a0, w.w, acc[0][3]);
            acc[1][0] = fmaf(a1, w.x, acc[1][0]); acc[1][1] = fmaf(a1, w.y, acc[1][1]);
            acc[1][2] = fmaf(a1, w.z, acc[1][2]); acc[1][3] = fmaf(a1, w.w, acc[1][3]);
            acc[2][0] = fmaf(a2, w.x, acc[2][0]); acc[2][1] = fmaf(a2, w.y, acc[2][1]);
            acc[2][2] = fmaf(a2, w.z, acc[2][2]); acc[2][3] = fmaf(a2, w.w, acc[2][3]);
            acc[3][0] = fmaf(a3, w.x, acc[3][0]); acc[3][1] = fmaf(a3, w.y, acc[3][1]);
            acc[3][2] = fmaf(a3, w.z, acc[3][2]); acc[3][3] = fmaf(a3, w.w, acc[3][3]);
        }
        const float4 bv = *reinterpret_cast<const float4*>(&bi[cg << 2]);
#pragma unroll
        for (int i = 0; i < 4; ++i) {
            h0r[i][0] = fmaxf(acc[i][0] + bv.x, 0.f);
            h0r[i][1] = fmaxf(acc[i][1] + bv.y, 0.f);
            h0r[i][2] = fmaxf(acc[i][2] + bv.z, 0.f);
            h0r[i][3] = fmaxf(acc[i][3] + bv.w, 0.f);
        }
        __syncthreads();                     // GEMM1 reads of A done before M overwrites
    }

    // stage M = agg[src] - H[rev]  (all tile-local H reads happen here)
    for (int f = t; f < 512; f += 256) {
        const int e = f >> 4, c8 = (f & 15) << 3;
        const float* ag = &agg[(size_t)s_src[e] * HID + c8];
        const float4 g0 = *reinterpret_cast<const float4*>(ag);
        const float4 g1 = *reinterpret_cast<const float4*>(ag + 4);
        const uint4 hh = *reinterpret_cast<const uint4*>(&H[(size_t)s_rev[e] * HID + c8]);
        float* m = &A[e][c8];
        m[0] = g0.x - bf2f(hh.x); m[1] = g0.y - bf2f(hh.x >> 16);
        m[2] = g0.z - bf2f(hh.y); m[3] = g0.w - bf2f(hh.y >> 16);
        m[4] = g1.x - bf2f(hh.z); m[5] = g1.y - bf2f(hh.z >> 16);
        m[6] = g1.z - bf2f(hh.w); m[7] = g1.w - bf2f(hh.w >> 16);
    }
    __syncthreads();
    float acc[4][4] = {};
#pragma unroll 4
    for (int k = 0; k < HID; ++k) {
        const float4 w = *reinterpret_cast<const float4*>(&Wh[k * HID + (cg << 2)]);
        const float a0 = A[eg * 4 + 0][k], a1 = A[eg * 4 + 1][k];
        const float a2 = A[eg * 4 + 2][k], a3 = A[eg * 4 + 3][k];
        acc[0][0] = fmaf(a0, w.x, acc[0][0]); acc[0][1] = fmaf(a0, w.y, acc[0][1]);
        acc[0][2] = fmaf(a0, w.z, acc[0][2]); acc[0][3] = fmaf(a0, w.w, acc[0][3]);
        acc[1][0] = fmaf(a1, w.x, acc[1][0]); acc[1][1] = fmaf(a1, w.y, acc[1][1]);
        acc[1][2] = fmaf(a1, w.z, acc[1][2]); acc[1][3] = fmaf(a1, w.w, acc[1][3]);
        acc[2][0] = fmaf(a2, w.x, acc[2][0]); acc[2][1] = fmaf(a2, w.y, acc[2][1]);
        acc[2][2] = fmaf(a2, w.z, acc[2][2]); acc[2][3] = fmaf(a2, w.w, acc[2][3]);
        acc[3][0] = fmaf(a3, w.x, acc[3][0]); acc[3][1] = fmaf(a3, w.y, acc[3][1]);
        acc[3][2] = fmaf(a3, w.z, acc[3][2]); acc[3][3] = fmaf(a3, w.w, acc[3][3]);
    }
    const float4 bv = *reinterpret_cast<const float4*>(&bh[cg << 2]);
#pragma unroll
    for (int i = 0; i < 4; ++i) {
        const int e = e0 + eg * 4 + i;
        float4 h0v;
        if (RECOMP) {
            h0v = make_float4(h0r[i][0], h0r[i][1], h0r[i][2], h0r[i][3]);
        } else {
            // H holds H0; this thread's slots are read only by itself
            const ushort4 hu = *reinterpret_cast<const ushort4*>(&H[(size_t)e * HID + (cg << 2)]);
            h0v = make_float4(bf2f(hu.x), bf2f(hu.y), bf2f(hu.z), bf2f(hu.w));
        }
        ushort4 o;
        o.x = f2bf(fmaxf(h0v.x + acc[i][0] + bv.x, 0.f));
        o.y = f2bf(fmaxf(h0v.y + acc[i][1] + bv.y, 0.f));
        o.z = f2bf(fmaxf(h0v.z + acc[i][2] + bv.z, 0.f));
        o.w = f2bf(fmaxf(h0v.w + acc[i][3] + bv.w, 0.f));
        *reinterpret_cast<ushort4*>(&H[(size_t)e * HID + (cg << 2)]) = o;
    }
}

// ----------------------------------------- out = relu([x; where(cnt==0,x,agg)] @ Wo + bo)
// agg aliases out (both = d_out): each block stages its agg rows to LDS
// before writing the same rows, so the in-place use is block-local safe.
__global__ __launch_bounds__(256) void k_out(const float* __restrict__ x,
                                             const float* agg,
                                             const int* __restrict__ cnt,
                                             const float* __restrict__ Wo,
                                             const float* __restrict__ bo,
                                             float* out) {
    __shared__ float A[32][2 * HID + 1];    // 32.9 KB
    __shared__ int s_cnt[32];
    const int n0 = blockIdx.x * 32;
    const int t = threadIdx.x;
    if (t < 32) s_cnt[t] = cnt[n0 + t];
    __syncthreads();
    for (int f = t; f < 1024; f += 256) {
        const int n = f >> 5, k4 = (f & 31) << 2;
        const float4 v = *reinterpret_cast<const float4*>(&x[(size_t)(n0 + n) * HID + k4]);
        float* a = &A[n][k4];
        a[0] = v.x; a[1] = v.y; a[2] = v.z; a[3] = v.w;
        float4 mv = v;
        if (s_cnt[n] > 0) mv = *reinterpret_cast<const float4*>(&agg[(size_t)(n0 + n) * HID + k4]);
        float* a2 = &A[n][HID + k4];
        a2[0] = mv.x; a2[1] = mv.y; a2[2] = mv.z; a2[3] = mv.w;
    }
    __syncthreads();
    const int ng = t >> 5, cg = t & 31;
    float acc[4][4] = {};
#pragma unroll 4
    for (int k = 0; k < 2 * HID; ++k) {
        const float4 w = *reinterpret_cast<const float4*>(&Wo[k * HID + (cg << 2)]);
        const float a0 = A[ng * 4 + 0][k], a1 = A[ng * 4 + 1][k];
        const float a2 = A[ng * 4 + 2][k], a3 = A[ng * 4 + 3][k];
        acc[0][0] = fmaf(a0, w.x, acc[0][0]); acc[0][1] = fmaf(a0, w.y, acc[0][1]);
        acc[0][2] = fmaf(a0, w.z, acc[0][2]); acc[0][3] = fmaf(a0, w.w, acc[0][3]);
        acc[1][0] = fmaf(a1, w.x, acc[1][0]); acc[1][1] = fmaf(a1, w.y, acc[1][1]);
        acc[1][2] = fmaf(a1, w.z, acc[1][2]); acc[1][3] = fmaf(a1, w.w, acc[1][3]);
        acc[2][0] = fmaf(a2, w.x, acc[2][0]); acc[2][1] = fmaf(a2, w.y, acc[2][1]);
        acc[2][2] = fmaf(a2, w.z, acc[2][2]); acc[2][3] = fmaf(a2, w.w, acc[2][3]);
        acc[3][0] = fmaf(a3, w.x, acc[3][0]); acc[3][1] = fmaf(a3, w.y, acc[3][1]);
        acc[3][2] = fmaf(a3, w.z, acc[3][2]); acc[3][3] = fmaf(a3, w.w, acc[3][3]);
    }
    const float4 bv = *reinterpret_cast<const float4*>(&bo[cg << 2]);
#pragma unroll
    for (int i = 0; i < 4; ++i) {
        const int n = n0 + ng * 4 + i;
        float4 o;
        o.x = fmaxf(acc[i][0] + bv.x, 0.f);
        o.y = fmaxf(acc[i][1] + bv.y, 0.f);
        o.z = fmaxf(acc[i][2] + bv.z, 0.f);
        o.w = fmaxf(acc[i][3] + bv.w, 0.f);
        *reinterpret_cast<float4*>(&out[(size_t)n * HID + (cg << 2)]) = o;
    }
}

// ---------------------------------------------------------------- launch
extern "C" void kernel_launch(void* const* d_in, const int* in_sizes, int n_in,
                              void* d_out, int out_size, void* d_ws, size_t ws_size,
                              hipStream_t stream) {
    const float* x  = (const float*)d_in[0];
    const float* ea = (const float*)d_in[1];
    const float* Wi = (const float*)d_in[2];
    const float* bi = (const float*)d_in[3];
    const float* Wh = (const float*)d_in[4];
    const float* bh = (const float*)d_in[5];
    const float* Wo = (const float*)d_in[6];
    const float* bo = (const float*)d_in[7];
    const int* ei   = (const int*)d_in[8];
    const int* rev  = (const int*)d_in[9];
    const int* src  = ei;
    const int* dst  = ei + N_EDGES;

    char* ws = (char*)d_ws;
    size_t off = 0;
    auto alloc = [&](size_t bytes) -> void* {
        void* p = ws + off;
        off += (bytes + 255) & ~(size_t)255;
        return p;
    };
    // total ~157 MB
    unsigned short* H = (unsigned short*)alloc((size_t)N_EDGES * HID * 2);
    int* cnt     = (int*)alloc((size_t)N_NODES * 4);
    int* rowptr  = (int*)alloc((size_t)(N_NODES + 1) * 4);
    int* wpos    = (int*)alloc((size_t)N_NODES * 4);
    int* bsum    = (int*)alloc(512);
    int* boff    = (int*)alloc(512);
    int* eidx    = (int*)alloc((size_t)N_EDGES * 4);
    float* agg   = (float*)d_out;           // reuse output buffer as agg scratch

    const int EB = (N_EDGES + 255) / 256;

    // CSR by dst (reused for all 3 aggregations)
    hipMemsetAsync(cnt, 0, (size_t)N_NODES * 4, stream);
    k_hist<<<EB, 256, 0, stream>>>(dst, cnt);
    k_blocksum<<<NB_CHUNKS, 256, 0, stream>>>(cnt, bsum);
    k_scan_bsum<<<1, 128, 0, stream>>>(bsum, boff, rowptr);
    k_scan_chunk<<<NB_CHUNKS, 256, 0, stream>>>(cnt, boff, rowptr, wpos);
    k_fill<<<EB, 256, 0, stream>>>(dst, wpos, eidx);

    // H := H0
    k_h0<<<N_EDGES / 32, 256, 0, stream>>>(x, ea, Wi, bi, src, H);

    // iteration 1: H holds H0 (read H0 from H)
    k_agg<<<N_NODES / 4, 256, 0, stream>>>(H, rowptr, eidx, agg);
    k_msg<0><<<N_EDGES / 32, 256, 0, stream>>>(x, ea, agg, Wi, bi, Wh, bh, src, rev, H);

    // iteration 2: recompute H0 inside k_msg
    k_agg<<<N_NODES / 4, 256, 0, stream>>>(H, rowptr, eidx, agg);
    k_msg<1><<<N_EDGES / 32, 256, 0, stream>>>(x, ea, agg, Wi, bi, Wh, bh, src, rev, H);

    // final aggregation + output GEMM (agg aliases out; k_out stages rows first)
    k_agg<<<N_NODES / 4, 256, 0, stream>>>(H, rowptr, eidx, agg);
    k_out<<<N_NODES / 32, 256, 0, stream>>>(x, agg, cnt, Wo, bo, (float*)d_out);
}

// Round 3
// 674.204 us; speedup vs baseline: 2.6506x; 2.6506x over previous
//
#include <hip/hip_runtime.h>
#include <hip/hip_bf16.h>

#define N_NODES 100000
#define N_EDGES 600000
#define HID 128
#define D_BOND 16
#define NB_CHUNKS 98            // ceil(100000/1024)

typedef __attribute__((ext_vector_type(8))) short bf16x8;
typedef __attribute__((ext_vector_type(4))) float f32x4;

__device__ __forceinline__ float bf2f(unsigned int u) {
    return __uint_as_float((u & 0xffffu) << 16);
}
__device__ __forceinline__ unsigned short f2bf(float f) {
    unsigned int x = __float_as_uint(f);
    x += 0x7fffu + ((x >> 16) & 1u);          // round-to-nearest-even
    return (unsigned short)(x >> 16);
}
__device__ __forceinline__ unsigned int pk2(float a, float b) {
    return (unsigned int)f2bf(a) | ((unsigned int)f2bf(b) << 16);
}

// LDS tile: 32 rows x 256 bf16 (512B row stride), XOR-swizzled 16B units.
// Swizzle spreads the 16-lane same-column fragment read across 8 bank-quads.
__device__ __forceinline__ void st16(unsigned char* tile, int row, int u, uint4 v) {
    *reinterpret_cast<uint4*>(tile + ((row * 512 + u * 16) ^ ((row & 7) << 4))) = v;
}
__device__ __forceinline__ bf16x8 ld_a(const unsigned char* tile, int row, int kbyte) {
    return *reinterpret_cast<const bf16x8*>(tile + ((row * 512 + kbyte) ^ ((row & 7) << 4)));
}

// wave-level 16x16x32 MFMA GEMM over the LDS tile.
// wave w: row-frag wr (rows 16wr..16wr+15), col-frags cb..cb+3 (cols 16cb..16cb+63)
// Wp layout: frag (kk*8 + c): 64 lanes x 8 bf16 contiguous (1KB).
template<int NK>
__device__ __forceinline__ void gemm_frag(const unsigned char* tile, const unsigned short* Wp,
                                          int wr, int cb, int l, f32x4 (&acc)[4]) {
    const int arow = 16 * wr + (l & 15);
    const int abyte0 = (l >> 4) * 16;
#pragma unroll
    for (int kk = 0; kk < NK; ++kk) {
        const bf16x8 a = ld_a(tile, arow, kk * 64 + abyte0);
#pragma unroll
        for (int c = 0; c < 4; ++c) {
            const bf16x8 b = *reinterpret_cast<const bf16x8*>(&Wp[(((kk * 8) + cb + c) * 64 + l) * 8]);
            acc[c] = __builtin_amdgcn_mfma_f32_16x16x32_bf16(a, b, acc[c], 0, 0, 0);
        }
    }
}

// ---------------------------------------------------------------- CSR build
__global__ __launch_bounds__(256) void k_hist(const int* __restrict__ dst,
                                              int* __restrict__ cnt) {
    int e = blockIdx.x * 256 + threadIdx.x;
    if (e < N_EDGES) atomicAdd(&cnt[dst[e]], 1);
}

__global__ __launch_bounds__(256) void k_blocksum(const int* __restrict__ cnt,
                                                  int* __restrict__ bsum) {
    __shared__ int red[256];
    const int b = blockIdx.x, t = threadIdx.x;
    const int base = b * 1024 + t * 4;
    int s = 0;
#pragma unroll
    for (int i = 0; i < 4; ++i) { int n = base + i; if (n < N_NODES) s += cnt[n]; }
    red[t] = s; __syncthreads();
    for (int o = 128; o > 0; o >>= 1) { if (t < o) red[t] += red[t + o]; __syncthreads(); }
    if (t == 0) bsum[b] = red[0];
}

__global__ __launch_bounds__(128) void k_scan_bsum(const int* __restrict__ bsum,
                                                   int* __restrict__ boff,
                                                   int* __restrict__ rowptr) {
    __shared__ int s[128];
    const int t = threadIdx.x;
    const int v = (t < NB_CHUNKS) ? bsum[t] : 0;
    s[t] = v; __syncthreads();
    for (int o = 1; o < 128; o <<= 1) {
        int add = 0; if (t >= o) add = s[t - o];
        __syncthreads();
        s[t] += add; __syncthreads();
    }
    if (t < NB_CHUNKS) boff[t] = s[t] - v;
    if (t == 0) rowptr[N_NODES] = N_EDGES;
}

__global__ __launch_bounds__(256) void k_scan_chunk(const int* __restrict__ cnt,
                                                    const int* __restrict__ boff,
                                                    int* __restrict__ rowptr,
                                                    int* __restrict__ wpos) {
    __shared__ int s[256];
    const int b = blockIdx.x, t = threadIdx.x;
    const int base = b * 1024 + t * 4;
    int v[4]; int ts = 0;
#pragma unroll
    for (int i = 0; i < 4; ++i) { int n = base + i; v[i] = (n < N_NODES) ? cnt[n] : 0; ts += v[i]; }
    s[t] = ts; __syncthreads();
    for (int o = 1; o < 256; o <<= 1) {
        int add = 0; if (t >= o) add = s[t - o];
        __syncthreads();
        s[t] += add; __syncthreads();
    }
    int run = s[t] - ts + boff[b];
#pragma unroll
    for (int i = 0; i < 4; ++i) {
        int n = base + i;
        if (n < N_NODES) { rowptr[n] = run; wpos[n] = run; }
        run += v[i];
    }
}

__global__ __launch_bounds__(256) void k_fill(const int* __restrict__ dst,
                                              int* __restrict__ wpos,
                                              int* __restrict__ eidx) {
    int e = blockIdx.x * 256 + threadIdx.x;
    if (e < N_EDGES) { int p = atomicAdd(&wpos[dst[e]], 1); eidx[p] = e; }
}

// -------------------------------------------------- weight prepack (f32 -> bf16 frags)
// frag element (kk, c, lane l, j) = W[kk*32 + 8*(l>>4) + j][16c + (l&15)], zero-padded.
// Wi: 5 ksteps (K=144 pad 160), Wh: 4 (K=128), Wo: 8 (K=256).
__global__ __launch_bounds__(256) void k_pack(const float* __restrict__ Wi,
                                              const float* __restrict__ Wh,
                                              const float* __restrict__ Wo,
                                              unsigned short* __restrict__ Pi,
                                              unsigned short* __restrict__ Ph,
                                              unsigned short* __restrict__ Po) {
    const int tid = blockIdx.x * 256 + threadIdx.x;     // exactly 8704 threads
    const float* W; unsigned short* P; int Krows, base;
    if (tid < 2560)      { W = Wi; P = Pi; Krows = 144; base = tid; }
    else if (tid < 4608) { W = Wh; P = Ph; Krows = 128; base = tid - 2560; }
    else                 { W = Wo; P = Po; Krows = 256; base = tid - 4608; }
    const int l = base & 63, fc = base >> 6;
    const int c = fc & 7, kk = fc >> 3;
    const int col = c * 16 + (l & 15);
    const int k0 = kk * 32 + (l >> 4) * 8;
    float v[8];
#pragma unroll
    for (int j = 0; j < 8; ++j) {
        const int k = k0 + j;
        v[j] = (k < Krows) ? W[(size_t)k * HID + col] : 0.f;
    }
    uint4 o;
    o.x = pk2(v[0], v[1]); o.y = pk2(v[2], v[3]);
    o.z = pk2(v[4], v[5]); o.w = pk2(v[6], v[7]);
    *reinterpret_cast<uint4*>(&P[(size_t)base * 8]) = o;
}

// ---------------- stage A2 = [x[src] | ea | 0] (32 x 160 bf16) into tile
__device__ __forceinline__ void stage_xe(unsigned char* tile, const float* __restrict__ x,
                                         const float* __restrict__ ea, const int* s_src,
                                         int e0, int t) {
    for (int f = t; f < 512; f += 256) {
        const int e = f >> 4, u = f & 15;
        const float* xp = &x[(size_t)s_src[e] * HID + u * 8];
        const float4 v0 = *reinterpret_cast<const float4*>(xp);
        const float4 v1 = *reinterpret_cast<const float4*>(xp + 4);
        uint4 o;
        o.x = pk2(v0.x, v0.y); o.y = pk2(v0.z, v0.w);
        o.z = pk2(v1.x, v1.y); o.w = pk2(v1.z, v1.w);
        st16(tile, e, u, o);
    }
    if (t < 64) {
        const int e = t >> 1, u = t & 1;
        const float* ep = &ea[(size_t)(e0 + e) * D_BOND + u * 8];
        const float4 v0 = *reinterpret_cast<const float4*>(ep);
        const float4 v1 = *reinterpret_cast<const float4*>(ep + 4);
        uint4 o;
        o.x = pk2(v0.x, v0.y); o.y = pk2(v0.z, v0.w);
        o.z = pk2(v1.x, v1.y); o.w = pk2(v1.z, v1.w);
        st16(tile, e, 16 + u, o);
    } else if (t < 128) {
        const int i = t - 64, e = i >> 1, u = i & 1;
        st16(tile, e, 18 + u, make_uint4(0, 0, 0, 0));
    }
}

// ------------------------------------------------------------ H = relu([x[src];ea] @ Wi + bi)
__global__ __launch_bounds__(256) void k_h0(const float* __restrict__ x,
                                            const float* __restrict__ ea,
                                            const unsigned short* __restrict__ Pi,
                                            const float* __restrict__ bi,
                                            const int* __restrict__ src,
                                            unsigned short* __restrict__ H) {
    __shared__ __align__(16) unsigned char tile[32 * 512];
    __shared__ int s_src[32];
    const int e0 = blockIdx.x * 32;
    const int t = threadIdx.x;
    if (t < 32) s_src[t] = src[e0 + t];
    __syncthreads();
    stage_xe(tile, x, ea, s_src, e0, t);
    __syncthreads();
    const int w = t >> 6, l = t & 63;
    const int wr = w & 1, cb = (w >> 1) * 4;
    f32x4 acc[4] = {{0.f,0.f,0.f,0.f},{0.f,0.f,0.f,0.f},{0.f,0.f,0.f,0.f},{0.f,0.f,0.f,0.f}};
    gemm_frag<5>(tile, Pi, wr, cb, l, acc);
    const int frow = 16 * wr + 4 * (l >> 4);
#pragma unroll
    for (int c = 0; c < 4; ++c) {
        const int col = ((cb + c) << 4) | (l & 15);
        const float bias = bi[col];
#pragma unroll
        for (int r = 0; r < 4; ++r) {
            H[(size_t)(e0 + frow + r) * HID + col] = f2bf(fmaxf(acc[c][r] + bias, 0.f));
        }
    }
}

// ------------------------------------------------------------ agg[n] = sum_{e:dst=n} H[e]  (bf16 out, 512B row stride)
__global__ __launch_bounds__(256) void k_agg(const unsigned short* __restrict__ H,
                                             const int* __restrict__ rowptr,
                                             const int* __restrict__ eidx,
                                             void* __restrict__ aggv) {
    const int wid = (blockIdx.x * 256 + threadIdx.x) >> 6;  // one wave per node
    const int lane = threadIdx.x & 63;
    if (wid >= N_NODES) return;
    const int beg = rowptr[wid], end = rowptr[wid + 1];
    float a0 = 0.f, a1 = 0.f;
    for (int j = beg; j < end; ++j) {
        const int e = eidx[j];
        const unsigned int p = *reinterpret_cast<const unsigned int*>(&H[(size_t)e * HID + lane * 2]);
        a0 += bf2f(p);
        a1 += bf2f(p >> 16);
    }
    *reinterpret_cast<unsigned int*>((char*)aggv + (size_t)wid * 512 + lane * 4) = pk2(a0, a1);
}

// ------------- H = relu(H0 + (agg[src]-H[rev]) @ Wh + bh), in place (rev = e^1, tile-local).
// RECOMP=0: H holds H0 (iter 1) — epilogue reads own H0 slots from H.
// RECOMP=1: recompute H0 via a K=160 MFMA pass first.
template<int RECOMP>
__global__ __launch_bounds__(256) void k_msg(const float* __restrict__ x,
                                             const float* __restrict__ ea,
                                             const void* __restrict__ aggv,
                                             const unsigned short* __restrict__ Pi,
                                             const float* __restrict__ bi,
                                             const unsigned short* __restrict__ Ph,
                                             const float* __restrict__ bh,
                                             const int* __restrict__ src,
                                             const int* __restrict__ rev,
                                             unsigned short* H) {
    __shared__ __align__(16) unsigned char tile[32 * 512];
    __shared__ int s_src[32], s_rev[32];
    const int e0 = blockIdx.x * 32;
    const int t = threadIdx.x;
    if (t < 32) { s_src[t] = src[e0 + t]; s_rev[t] = rev[e0 + t]; }
    __syncthreads();
    const int w = t >> 6, l = t & 63;
    const int wr = w & 1, cb = (w >> 1) * 4;
    float h0r[4][4];

    if (RECOMP) {
        stage_xe(tile, x, ea, s_src, e0, t);
        __syncthreads();
        f32x4 acc[4] = {{0.f,0.f,0.f,0.f},{0.f,0.f,0.f,0.f},{0.f,0.f,0.f,0.f},{0.f,0.f,0.f,0.f}};
        gemm_frag<5>(tile, Pi, wr, cb, l, acc);
#pragma unroll
        for (int c = 0; c < 4; ++c) {
            const float bias = bi[((cb + c) << 4) | (l & 15)];
#pragma unroll
            for (int r = 0; r < 4; ++r) h0r[c][r] = fmaxf(acc[c][r] + bias, 0.f);
        }
        __syncthreads();     // GEMM1 A-reads done before M overwrites tile
    }

    // stage M = agg[src] - H[rev]  (all tile-local H reads happen before the sync)
    for (int f = t; f < 512; f += 256) {
        const int e = f >> 4, u = f & 15;
        const unsigned short* ap =
            reinterpret_cast<const unsigned short*>((const char*)aggv + (size_t)s_src[e] * 512) + u * 8;
        const uint4 av = *reinterpret_cast<const uint4*>(ap);
        const uint4 hv = *reinterpret_cast<const uint4*>(&H[(size_t)s_rev[e] * HID + u * 8]);
        uint4 o;
        o.x = pk2(bf2f(av.x) - bf2f(hv.x), bf2f(av.x >> 16) - bf2f(hv.x >> 16));
        o.y = pk2(bf2f(av.y) - bf2f(hv.y), bf2f(av.y >> 16) - bf2f(hv.y >> 16));
        o.z = pk2(bf2f(av.z) - bf2f(hv.z), bf2f(av.z >> 16) - bf2f(hv.z >> 16));
        o.w = pk2(bf2f(av.w) - bf2f(hv.w), bf2f(av.w >> 16) - bf2f(hv.w >> 16));
        st16(tile, e, u, o);
    }
    __syncthreads();
    f32x4 acc[4] = {{0.f,0.f,0.f,0.f},{0.f,0.f,0.f,0.f},{0.f,0.f,0.f,0.f},{0.f,0.f,0.f,0.f}};
    gemm_frag<4>(tile, Ph, wr, cb, l, acc);
    const int frow = 16 * wr + 4 * (l >> 4);
#pragma unroll
    for (int c = 0; c < 4; ++c) {
        const int col = ((cb + c) << 4) | (l & 15);
        const float bias = bh[col];
#pragma unroll
        for (int r = 0; r < 4; ++r) {
            const size_t idx = (size_t)(e0 + frow + r) * HID + col;
            const float h0v = RECOMP ? h0r[c][r] : bf2f((unsigned int)H[idx]);
            H[idx] = f2bf(fmaxf(h0v + acc[c][r] + bias, 0.f));
        }
    }
}

// ----------------------------------------- out = relu([x; where(cnt==0,x,agg)] @ Wo + bo)
// agg (bf16, 512B stride) aliases d_out row-for-row: stage-then-write is block-local safe.
__global__ __launch_bounds__(256) void k_out(const float* __restrict__ x,
                                             const void* aggv,
                                             const int* __restrict__ cnt,
                                             const unsigned short* __restrict__ Po,
                                             const float* __restrict__ bo,
                                             float* out) {
    __shared__ __align__(16) unsigned char tile[32 * 512];
    __shared__ int s_cnt[32];
    const int n0 = blockIdx.x * 32;
    const int t = threadIdx.x;
    if (t < 32) s_cnt[t] = cnt[n0 + t];
    __syncthreads();
    for (int f = t; f < 1024; f += 256) {
        const int e = f >> 5, u = f & 31;
        uint4 o;
        if (u >= 16 && s_cnt[e] > 0) {
            o = *reinterpret_cast<const uint4*>((const char*)aggv + (size_t)(n0 + e) * 512 + (u - 16) * 16);
        } else {
            const int k8 = (u & 15) * 8;
            const float* xp = &x[(size_t)(n0 + e) * HID + k8];
            const float4 v0 = *reinterpret_cast<const float4*>(xp);
            const float4 v1 = *reinterpret_cast<const float4*>(xp + 4);
            o.x = pk2(v0.x, v0.y); o.y = pk2(v0.z, v0.w);
            o.z = pk2(v1.x, v1.y); o.w = pk2(v1.z, v1.w);
        }
        st16(tile, e, u, o);
    }
    __syncthreads();
    const int w = t >> 6, l = t & 63;
    const int wr = w & 1, cb = (w >> 1) * 4;
    f32x4 acc[4] = {{0.f,0.f,0.f,0.f},{0.f,0.f,0.f,0.f},{0.f,0.f,0.f,0.f},{0.f,0.f,0.f,0.f}};
    gemm_frag<8>(tile, Po, wr, cb, l, acc);
    const int frow = 16 * wr + 4 * (l >> 4);
#pragma unroll
    for (int c = 0; c < 4; ++c) {
        const int col = ((cb + c) << 4) | (l & 15);
        const float bias = bo[col];
#pragma unroll
        for (int r = 0; r < 4; ++r) {
            out[(size_t)(n0 + frow + r) * HID + col] = fmaxf(acc[c][r] + bias, 0.f);
        }
    }
}

// ---------------------------------------------------------------- launch
extern "C" void kernel_launch(void* const* d_in, const int* in_sizes, int n_in,
                              void* d_out, int out_size, void* d_ws, size_t ws_size,
                              hipStream_t stream) {
    const float* x  = (const float*)d_in[0];
    const float* ea = (const float*)d_in[1];
    const float* Wi = (const float*)d_in[2];
    const float* bi = (const float*)d_in[3];
    const float* Wh = (const float*)d_in[4];
    const float* bh = (const float*)d_in[5];
    const float* Wo = (const float*)d_in[6];
    const float* bo = (const float*)d_in[7];
    const int* ei   = (const int*)d_in[8];
    const int* rev  = (const int*)d_in[9];
    const int* src  = ei;
    const int* dst  = ei + N_EDGES;

    char* ws = (char*)d_ws;
    size_t off = 0;
    auto alloc = [&](size_t bytes) -> void* {
        void* p = ws + off;
        off += (bytes + 255) & ~(size_t)255;
        return p;
    };
    // total ~157 MB (same footprint as the passing round-2 plan)
    unsigned short* H  = (unsigned short*)alloc((size_t)N_EDGES * HID * 2);
    int* cnt     = (int*)alloc((size_t)N_NODES * 4);
    int* rowptr  = (int*)alloc((size_t)(N_NODES + 1) * 4);
    int* wpos    = (int*)alloc((size_t)N_NODES * 4);
    int* bsum    = (int*)alloc(512);
    int* boff    = (int*)alloc(512);
    int* eidx    = (int*)alloc((size_t)N_EDGES * 4);
    unsigned short* Pi = (unsigned short*)alloc(2560 * 8 * 2);  // 5 ksteps
    unsigned short* Ph = (unsigned short*)alloc(2048 * 8 * 2);  // 4 ksteps
    unsigned short* Po = (unsigned short*)alloc(4096 * 8 * 2);  // 8 ksteps
    void* agg = d_out;   // bf16 agg rows at 512B stride, aliases f32 output rows

    const int EB = (N_EDGES + 255) / 256;

    // CSR by dst (reused for all 3 aggregations)
    hipMemsetAsync(cnt, 0, (size_t)N_NODES * 4, stream);
    k_hist<<<EB, 256, 0, stream>>>(dst, cnt);
    k_blocksum<<<NB_CHUNKS, 256, 0, stream>>>(cnt, bsum);
    k_scan_bsum<<<1, 128, 0, stream>>>(bsum, boff, rowptr);
    k_scan_chunk<<<NB_CHUNKS, 256, 0, stream>>>(cnt, boff, rowptr, wpos);
    k_fill<<<EB, 256, 0, stream>>>(dst, wpos, eidx);

    // weight prepack for MFMA fragments
    k_pack<<<34, 256, 0, stream>>>(Wi, Wh, Wo, Pi, Ph, Po);

    // H := H0
    k_h0<<<N_EDGES / 32, 256, 0, stream>>>(x, ea, Pi, bi, src, H);

    // iteration 1: H holds H0
    k_agg<<<N_NODES / 4, 256, 0, stream>>>(H, rowptr, eidx, agg);
    k_msg<0><<<N_EDGES / 32, 256, 0, stream>>>(x, ea, agg, Pi, bi, Ph, bh, src, rev, H);

    // iteration 2: recompute H0 inside k_msg
    k_agg<<<N_NODES / 4, 256, 0, stream>>>(H, rowptr, eidx, agg);
    k_msg<1><<<N_EDGES / 32, 256, 0, stream>>>(x, ea, agg, Pi, bi, Ph, bh, src, rev, H);

    // final aggregation + output GEMM
    k_agg<<<N_NODES / 4, 256, 0, stream>>>(H, rowptr, eidx, agg);
    k_out<<<N_NODES / 32, 256, 0, stream>>>(x, agg, cnt, Po, bo, (float*)d_out);
}

// Round 4
// 672.761 us; speedup vs baseline: 2.6563x; 1.0021x over previous
//
#include <hip/hip_runtime.h>
#include <hip/hip_bf16.h>

#define N_NODES 100000
#define N_EDGES 600000
#define HID 128
#define D_BOND 16
#define NB_CHUNKS 98            // ceil(100000/1024)

typedef __attribute__((ext_vector_type(8))) short bf16x8;
typedef __attribute__((ext_vector_type(4))) float f32x4;

__device__ __forceinline__ float bf2f(unsigned int u) {
    return __uint_as_float((u & 0xffffu) << 16);
}
__device__ __forceinline__ unsigned short f2bf(float f) {
    unsigned int x = __float_as_uint(f);
    x += 0x7fffu + ((x >> 16) & 1u);          // round-to-nearest-even
    return (unsigned short)(x >> 16);
}
__device__ __forceinline__ unsigned int pk2(float a, float b) {
    return (unsigned int)f2bf(a) | ((unsigned int)f2bf(b) << 16);
}

// LDS tile: rows x 256 bf16 (512B row stride), XOR-swizzled 16B units.
__device__ __forceinline__ void st16(unsigned char* tile, int row, int u, uint4 v) {
    *reinterpret_cast<uint4*>(tile + ((row * 512 + u * 16) ^ ((row & 7) << 4))) = v;
}
__device__ __forceinline__ bf16x8 ld_a(const unsigned char* tile, int row, int kbyte) {
    return *reinterpret_cast<const bf16x8*>(tile + ((row * 512 + kbyte) ^ ((row & 7) << 4)));
}

// single-row-frag GEMM (k_out): wave w -> wr = w&1, cb = (w>>1)*4
template<int NK>
__device__ __forceinline__ void gemm_frag(const unsigned char* tile, const unsigned short* Wp,
                                          int wr, int cb, int l, f32x4 (&acc)[4]) {
    const int arow = 16 * wr + (l & 15);
    const int abyte0 = (l >> 4) * 16;
#pragma unroll
    for (int kk = 0; kk < NK; ++kk) {
        const bf16x8 a = ld_a(tile, arow, kk * 64 + abyte0);
#pragma unroll
        for (int c = 0; c < 4; ++c) {
            const bf16x8 b = *reinterpret_cast<const bf16x8*>(&Wp[(((kk * 8) + cb + c) * 64 + l) * 8]);
            acc[c] = __builtin_amdgcn_mfma_f32_16x16x32_bf16(a, b, acc[c], 0, 0, 0);
        }
    }
}

// dual-row-frag GEMM (64-row tiles): wave w -> cb = (w&1)*4, wr0 = (w>>1)*2
template<int NK>
__device__ __forceinline__ void gemm_frag2(const unsigned char* tile, const unsigned short* Wp,
                                           int wr0, int cb, int l, f32x4 (&acc)[2][4]) {
    const int abyte0 = (l >> 4) * 16;
    const int ar0 = 16 * wr0 + (l & 15);
#pragma unroll
    for (int kk = 0; kk < NK; ++kk) {
        const bf16x8 a0 = ld_a(tile, ar0, kk * 64 + abyte0);
        const bf16x8 a1 = ld_a(tile, ar0 + 16, kk * 64 + abyte0);
#pragma unroll
        for (int c = 0; c < 4; ++c) {
            const bf16x8 b = *reinterpret_cast<const bf16x8*>(&Wp[(((kk * 8) + cb + c) * 64 + l) * 8]);
            acc[0][c] = __builtin_amdgcn_mfma_f32_16x16x32_bf16(a0, b, acc[0][c], 0, 0, 0);
            acc[1][c] = __builtin_amdgcn_mfma_f32_16x16x32_bf16(a1, b, acc[1][c], 0, 0, 0);
        }
    }
}

// ---------------------------------------------------------------- CSR build
__global__ __launch_bounds__(256) void k_hist(const int* __restrict__ dst,
                                              int* __restrict__ cnt) {
    int e = blockIdx.x * 256 + threadIdx.x;
    if (e < N_EDGES) atomicAdd(&cnt[dst[e]], 1);
}

__global__ __launch_bounds__(256) void k_blocksum(const int* __restrict__ cnt,
                                                  int* __restrict__ bsum) {
    __shared__ int red[256];
    const int b = blockIdx.x, t = threadIdx.x;
    const int base = b * 1024 + t * 4;
    int s = 0;
#pragma unroll
    for (int i = 0; i < 4; ++i) { int n = base + i; if (n < N_NODES) s += cnt[n]; }
    red[t] = s; __syncthreads();
    for (int o = 128; o > 0; o >>= 1) { if (t < o) red[t] += red[t + o]; __syncthreads(); }
    if (t == 0) bsum[b] = red[0];
}

__global__ __launch_bounds__(128) void k_scan_bsum(const int* __restrict__ bsum,
                                                   int* __restrict__ boff,
                                                   int* __restrict__ rowptr) {
    __shared__ int s[128];
    const int t = threadIdx.x;
    const int v = (t < NB_CHUNKS) ? bsum[t] : 0;
    s[t] = v; __syncthreads();
    for (int o = 1; o < 128; o <<= 1) {
        int add = 0; if (t >= o) add = s[t - o];
        __syncthreads();
        s[t] += add; __syncthreads();
    }
    if (t < NB_CHUNKS) boff[t] = s[t] - v;
    if (t == 0) rowptr[N_NODES] = N_EDGES;
}

__global__ __launch_bounds__(256) void k_scan_chunk(const int* __restrict__ cnt,
                                                    const int* __restrict__ boff,
                                                    int* __restrict__ rowptr,
                                                    int* __restrict__ wpos) {
    __shared__ int s[256];
    const int b = blockIdx.x, t = threadIdx.x;
    const int base = b * 1024 + t * 4;
    int v[4]; int ts = 0;
#pragma unroll
    for (int i = 0; i < 4; ++i) { int n = base + i; v[i] = (n < N_NODES) ? cnt[n] : 0; ts += v[i]; }
    s[t] = ts; __syncthreads();
    for (int o = 1; o < 256; o <<= 1) {
        int add = 0; if (t >= o) add = s[t - o];
        __syncthreads();
        s[t] += add; __syncthreads();
    }
    int run = s[t] - ts + boff[b];
#pragma unroll
    for (int i = 0; i < 4; ++i) {
        int n = base + i;
        if (n < N_NODES) { rowptr[n] = run; wpos[n] = run; }
        run += v[i];
    }
}

__global__ __launch_bounds__(256) void k_fill(const int* __restrict__ dst,
                                              int* __restrict__ wpos,
                                              int* __restrict__ eidx) {
    int e = blockIdx.x * 256 + threadIdx.x;
    if (e < N_EDGES) { int p = atomicAdd(&wpos[dst[e]], 1); eidx[p] = e; }
}

// -------------------------------------------------- x -> bf16 prepack
__global__ __launch_bounds__(256) void k_xcvt(const float* __restrict__ x,
                                              unsigned short* __restrict__ xbf) {
    const size_t i = (size_t)(blockIdx.x * 256 + threadIdx.x) * 8;   // 6250 blocks exact
    const float4 v0 = *reinterpret_cast<const float4*>(&x[i]);
    const float4 v1 = *reinterpret_cast<const float4*>(&x[i + 4]);
    uint4 o;
    o.x = pk2(v0.x, v0.y); o.y = pk2(v0.z, v0.w);
    o.z = pk2(v1.x, v1.y); o.w = pk2(v1.z, v1.w);
    *reinterpret_cast<uint4*>(&xbf[i]) = o;
}

// -------------------------------------------------- weight prepack (f32 -> bf16 frags)
__global__ __launch_bounds__(256) void k_pack(const float* __restrict__ Wi,
                                              const float* __restrict__ Wh,
                                              const float* __restrict__ Wo,
                                              unsigned short* __restrict__ Pi,
                                              unsigned short* __restrict__ Ph,
                                              unsigned short* __restrict__ Po) {
    const int tid = blockIdx.x * 256 + threadIdx.x;     // exactly 8704 threads
    const float* W; unsigned short* P; int Krows, base;
    if (tid < 2560)      { W = Wi; P = Pi; Krows = 144; base = tid; }
    else if (tid < 4608) { W = Wh; P = Ph; Krows = 128; base = tid - 2560; }
    else                 { W = Wo; P = Po; Krows = 256; base = tid - 4608; }
    const int l = base & 63, fc = base >> 6;
    const int c = fc & 7, kk = fc >> 3;
    const int col = c * 16 + (l & 15);
    const int k0 = kk * 32 + (l >> 4) * 8;
    float v[8];
#pragma unroll
    for (int j = 0; j < 8; ++j) {
        const int k = k0 + j;
        v[j] = (k < Krows) ? W[(size_t)k * HID + col] : 0.f;
    }
    uint4 o;
    o.x = pk2(v[0], v[1]); o.y = pk2(v[2], v[3]);
    o.z = pk2(v[4], v[5]); o.w = pk2(v[6], v[7]);
    *reinterpret_cast<uint4*>(&P[(size_t)base * 8]) = o;
}

// ---------------- stage A = [xbf[src] | ea | 0] (64 x 160 bf16, pad to 256) into tile
__device__ __forceinline__ void stage_xe64(unsigned char* tile, const unsigned short* __restrict__ xbf,
                                           const float* __restrict__ ea, const int* s_src,
                                           int e0, int t) {
#pragma unroll
    for (int f = t; f < 1024; f += 256) {
        const int e = f >> 4, u = f & 15;
        const uint4 v = *reinterpret_cast<const uint4*>(&xbf[(size_t)s_src[e] * HID + u * 8]);
        st16(tile, e, u, v);
    }
    if (t < 128) {
        const int e = t >> 1, u = t & 1;
        const float* ep = &ea[(size_t)(e0 + e) * D_BOND + u * 8];
        const float4 v0 = *reinterpret_cast<const float4*>(ep);
        const float4 v1 = *reinterpret_cast<const float4*>(ep + 4);
        uint4 o;
        o.x = pk2(v0.x, v0.y); o.y = pk2(v0.z, v0.w);
        o.z = pk2(v1.x, v1.y); o.w = pk2(v1.z, v1.w);
        st16(tile, e, 16 + u, o);
    } else {
        const int i = t - 128, e = i >> 1, u = i & 1;
        st16(tile, e, 18 + u, make_uint4(0, 0, 0, 0));
    }
}

// ------------------------------------------------------------ H = relu([x[src];ea] @ Wi + bi)
__global__ __launch_bounds__(256) void k_h0(const unsigned short* __restrict__ xbf,
                                            const float* __restrict__ ea,
                                            const unsigned short* __restrict__ Pi,
                                            const float* __restrict__ bi,
                                            const int* __restrict__ src,
                                            unsigned short* __restrict__ H) {
    __shared__ __align__(16) unsigned char tile[64 * 512];
    __shared__ int s_src[64];
    const int e0 = blockIdx.x * 64;
    const int t = threadIdx.x;
    if (t < 64) s_src[t] = src[e0 + t];
    __syncthreads();
    stage_xe64(tile, xbf, ea, s_src, e0, t);
    __syncthreads();
    const int w = t >> 6, l = t & 63;
    const int cb = (w & 1) * 4, wr0 = (w >> 1) * 2;
    f32x4 acc[2][4] = {};
    gemm_frag2<5>(tile, Pi, wr0, cb, l, acc);
#pragma unroll
    for (int r = 0; r < 2; ++r) {
        const int frow = 16 * (wr0 + r) + 4 * (l >> 4);
#pragma unroll
        for (int c = 0; c < 4; ++c) {
            const int col = ((cb + c) << 4) | (l & 15);
            const float bias = bi[col];
#pragma unroll
            for (int rr = 0; rr < 4; ++rr) {
                H[(size_t)(e0 + frow + rr) * HID + col] = f2bf(fmaxf(acc[r][c][rr] + bias, 0.f));
            }
        }
    }
}

// ------------------------------------------------------------ agg[n] = sum_{e:dst=n} H[e]  (bf16 out, 512B row stride)
__global__ __launch_bounds__(256) void k_agg(const unsigned short* __restrict__ H,
                                             const int* __restrict__ rowptr,
                                             const int* __restrict__ eidx,
                                             void* __restrict__ aggv) {
    const int wid = (blockIdx.x * 256 + threadIdx.x) >> 6;  // one wave per node
    const int lane = threadIdx.x & 63;
    if (wid >= N_NODES) return;
    const int beg = rowptr[wid], end = rowptr[wid + 1];
    float a0 = 0.f, a1 = 0.f;
    for (int j = beg; j < end; ++j) {
        const int e = eidx[j];
        const unsigned int p = *reinterpret_cast<const unsigned int*>(&H[(size_t)e * HID + lane * 2]);
        a0 += bf2f(p);
        a1 += bf2f(p >> 16);
    }
    *reinterpret_cast<unsigned int*>((char*)aggv + (size_t)wid * 512 + lane * 4) = pk2(a0, a1);
}

// ------------- H = relu(H0 + (agg[src]-H[rev]) @ Wh + bh), in place (rev = e^1, tile-local).
// RECOMP=0: H holds H0 (iter 1) — epilogue reads own H0 slots from H.
// RECOMP=1: recompute H0 via a K=160 MFMA pass first.
template<int RECOMP>
__global__ __launch_bounds__(256) void k_msg(const unsigned short* __restrict__ xbf,
                                             const float* __restrict__ ea,
                                             const void* __restrict__ aggv,
                                             const unsigned short* __restrict__ Pi,
                                             const float* __restrict__ bi,
                                             const unsigned short* __restrict__ Ph,
                                             const float* __restrict__ bh,
                                             const int* __restrict__ src,
                                             const int* __restrict__ rev,
                                             unsigned short* H) {
    __shared__ __align__(16) unsigned char tile[64 * 512];
    __shared__ int s_src[64], s_rev[64];
    const int e0 = blockIdx.x * 64;
    const int t = threadIdx.x;
    if (t < 64) { s_src[t] = src[e0 + t]; s_rev[t] = rev[e0 + t]; }
    __syncthreads();
    const int w = t >> 6, l = t & 63;
    const int cb = (w & 1) * 4, wr0 = (w >> 1) * 2;
    float h0r[2][4][4];

    if (RECOMP) {
        stage_xe64(tile, xbf, ea, s_src, e0, t);
        __syncthreads();
        f32x4 acc[2][4] = {};
        gemm_frag2<5>(tile, Pi, wr0, cb, l, acc);
#pragma unroll
        for (int r = 0; r < 2; ++r)
#pragma unroll
            for (int c = 0; c < 4; ++c) {
                const float bias = bi[((cb + c) << 4) | (l & 15)];
#pragma unroll
                for (int rr = 0; rr < 4; ++rr) h0r[r][c][rr] = fmaxf(acc[r][c][rr] + bias, 0.f);
            }
        __syncthreads();     // GEMM1 A-reads done before M overwrites tile
    }

    // stage M = agg[src] - H[rev]  (all tile-local H reads happen before the sync)
#pragma unroll
    for (int f = t; f < 1024; f += 256) {
        const int e = f >> 4, u = f & 15;
        const unsigned short* ap =
            reinterpret_cast<const unsigned short*>((const char*)aggv + (size_t)s_src[e] * 512) + u * 8;
        const uint4 av = *reinterpret_cast<const uint4*>(ap);
        const uint4 hv = *reinterpret_cast<const uint4*>(&H[(size_t)s_rev[e] * HID + u * 8]);
        uint4 o;
        o.x = pk2(bf2f(av.x) - bf2f(hv.x), bf2f(av.x >> 16) - bf2f(hv.x >> 16));
        o.y = pk2(bf2f(av.y) - bf2f(hv.y), bf2f(av.y >> 16) - bf2f(hv.y >> 16));
        o.z = pk2(bf2f(av.z) - bf2f(hv.z), bf2f(av.z >> 16) - bf2f(hv.z >> 16));
        o.w = pk2(bf2f(av.w) - bf2f(hv.w), bf2f(av.w >> 16) - bf2f(hv.w >> 16));
        st16(tile, e, u, o);
    }
    __syncthreads();
    f32x4 acc[2][4] = {};
    gemm_frag2<4>(tile, Ph, wr0, cb, l, acc);
#pragma unroll
    for (int r = 0; r < 2; ++r) {
        const int frow = 16 * (wr0 + r) + 4 * (l >> 4);
#pragma unroll
        for (int c = 0; c < 4; ++c) {
            const int col = ((cb + c) << 4) | (l & 15);
            const float bias = bh[col];
#pragma unroll
            for (int rr = 0; rr < 4; ++rr) {
                const size_t idx = (size_t)(e0 + frow + rr) * HID + col;
                const float h0v = RECOMP ? h0r[r][c][rr] : bf2f((unsigned int)H[idx]);
                H[idx] = f2bf(fmaxf(h0v + acc[r][c][rr] + bias, 0.f));
            }
        }
    }
}

// ----------------------------------------- out = relu([x; where(cnt==0,x,agg)] @ Wo + bo)
// agg (bf16, 512B stride) aliases d_out row-for-row: stage-then-write is block-local safe.
__global__ __launch_bounds__(256) void k_out(const float* __restrict__ x,
                                             const void* aggv,
                                             const int* __restrict__ cnt,
                                             const unsigned short* __restrict__ Po,
                                             const float* __restrict__ bo,
                                             float* out) {
    __shared__ __align__(16) unsigned char tile[32 * 512];
    __shared__ int s_cnt[32];
    const int n0 = blockIdx.x * 32;
    const int t = threadIdx.x;
    if (t < 32) s_cnt[t] = cnt[n0 + t];
    __syncthreads();
    for (int f = t; f < 1024; f += 256) {
        const int e = f >> 5, u = f & 31;
        uint4 o;
        if (u >= 16 && s_cnt[e] > 0) {
            o = *reinterpret_cast<const uint4*>((const char*)aggv + (size_t)(n0 + e) * 512 + (u - 16) * 16);
        } else {
            const int k8 = (u & 15) * 8;
            const float* xp = &x[(size_t)(n0 + e) * HID + k8];
            const float4 v0 = *reinterpret_cast<const float4*>(xp);
            const float4 v1 = *reinterpret_cast<const float4*>(xp + 4);
            o.x = pk2(v0.x, v0.y); o.y = pk2(v0.z, v0.w);
            o.z = pk2(v1.x, v1.y); o.w = pk2(v1.z, v1.w);
        }
        st16(tile, e, u, o);
    }
    __syncthreads();
    const int w = t >> 6, l = t & 63;
    const int wr = w & 1, cb = (w >> 1) * 4;
    f32x4 acc[4] = {};
    gemm_frag<8>(tile, Po, wr, cb, l, acc);
    const int frow = 16 * wr + 4 * (l >> 4);
#pragma unroll
    for (int c = 0; c < 4; ++c) {
        const int col = ((cb + c) << 4) | (l & 15);
        const float bias = bo[col];
#pragma unroll
        for (int r = 0; r < 4; ++r) {
            out[(size_t)(n0 + frow + r) * HID + col] = fmaxf(acc[c][r] + bias, 0.f);
        }
    }
}

// ---------------------------------------------------------------- launch
extern "C" void kernel_launch(void* const* d_in, const int* in_sizes, int n_in,
                              void* d_out, int out_size, void* d_ws, size_t ws_size,
                              hipStream_t stream) {
    const float* x  = (const float*)d_in[0];
    const float* ea = (const float*)d_in[1];
    const float* Wi = (const float*)d_in[2];
    const float* bi = (const float*)d_in[3];
    const float* Wh = (const float*)d_in[4];
    const float* bh = (const float*)d_in[5];
    const float* Wo = (const float*)d_in[6];
    const float* bo = (const float*)d_in[7];
    const int* ei   = (const int*)d_in[8];
    const int* rev  = (const int*)d_in[9];
    const int* src  = ei;
    const int* dst  = ei + N_EDGES;

    char* ws = (char*)d_ws;
    size_t off = 0;
    auto alloc = [&](size_t bytes) -> void* {
        void* p = ws + off;
        off += (bytes + 255) & ~(size_t)255;
        return p;
    };
    // total ~183 MB
    unsigned short* H  = (unsigned short*)alloc((size_t)N_EDGES * HID * 2);
    unsigned short* xbf = (unsigned short*)alloc((size_t)N_NODES * HID * 2);
    int* cnt     = (int*)alloc((size_t)N_NODES * 4);
    int* rowptr  = (int*)alloc((size_t)(N_NODES + 1) * 4);
    int* wpos    = (int*)alloc((size_t)N_NODES * 4);
    int* bsum    = (int*)alloc(512);
    int* boff    = (int*)alloc(512);
    int* eidx    = (int*)alloc((size_t)N_EDGES * 4);
    unsigned short* Pi = (unsigned short*)alloc(2560 * 8 * 2);  // 5 ksteps
    unsigned short* Ph = (unsigned short*)alloc(2048 * 8 * 2);  // 4 ksteps
    unsigned short* Po = (unsigned short*)alloc(4096 * 8 * 2);  // 8 ksteps
    void* agg = d_out;   // bf16 agg rows at 512B stride, aliases f32 output rows

    const int EB = (N_EDGES + 255) / 256;

    // CSR by dst (reused for all 3 aggregations)
    hipMemsetAsync(cnt, 0, (size_t)N_NODES * 4, stream);
    k_hist<<<EB, 256, 0, stream>>>(dst, cnt);
    k_blocksum<<<NB_CHUNKS, 256, 0, stream>>>(cnt, bsum);
    k_scan_bsum<<<1, 128, 0, stream>>>(bsum, boff, rowptr);
    k_scan_chunk<<<NB_CHUNKS, 256, 0, stream>>>(cnt, boff, rowptr, wpos);
    k_fill<<<EB, 256, 0, stream>>>(dst, wpos, eidx);

    // prepacks
    k_xcvt<<<6250, 256, 0, stream>>>(x, xbf);
    k_pack<<<34, 256, 0, stream>>>(Wi, Wh, Wo, Pi, Ph, Po);

    // H := H0
    k_h0<<<N_EDGES / 64, 256, 0, stream>>>(xbf, ea, Pi, bi, src, H);

    // iteration 1: H holds H0
    k_agg<<<N_NODES / 4, 256, 0, stream>>>(H, rowptr, eidx, agg);
    k_msg<0><<<N_EDGES / 64, 256, 0, stream>>>(xbf, ea, agg, Pi, bi, Ph, bh, src, rev, H);

    // iteration 2: recompute H0 inside k_msg
    k_agg<<<N_NODES / 4, 256, 0, stream>>>(H, rowptr, eidx, agg);
    k_msg<1><<<N_EDGES / 64, 256, 0, stream>>>(xbf, ea, agg, Pi, bi, Ph, bh, src, rev, H);

    // final aggregation + output GEMM
    k_agg<<<N_NODES / 4, 256, 0, stream>>>(H, rowptr, eidx, agg);
    k_out<<<N_NODES / 32, 256, 0, stream>>>(x, agg, cnt, Po, bo, (float*)d_out);
}